// Round 1
// baseline (155.957 us; speedup 1.0000x reference)
//
#include <hip/hip_runtime.h>

// SupConLoss on MI355X.
// features: [4096, 2, 128] fp32; labels: [4096] int; out: 1 fp32 scalar.
//
// ws layout:
//   [0, 2 MB)        nf       : 8192 x 128 bf16 (normalized, view-major: i = v*B + b)
//   [2 MB, +32 KB)   neg_sum  : 8192 f32
//   [2 MB + 32 KB)   total    : 1 f32
// ws needed: ~2.1 MB.

#define BATCH 4096
#define NN    8192
#define DD    128

typedef __attribute__((ext_vector_type(8))) short bf16x8;   // 8 bf16 = 4 VGPRs (MFMA A/B frag)
typedef __attribute__((ext_vector_type(4))) float f32x4;    // MFMA C/D frag

__device__ __forceinline__ unsigned short f2bf(float f) {
    unsigned u = __float_as_uint(f);
    u += 0x7FFF + ((u >> 16) & 1);          // round to nearest even
    return (unsigned short)(u >> 16);
}

__global__ void k_zero(float* p, int n) {
    int i = blockIdx.x * 256 + threadIdx.x;
    if (i < n) p[i] = 0.0f;
}

// One wave per row: load 128 fp32, reduce sumsq across 64 lanes, write 128 bf16.
__global__ void k_normalize(const float* __restrict__ feat, unsigned short* __restrict__ nf) {
    int wave = threadIdx.x >> 6, lane = threadIdx.x & 63;
    int row = blockIdx.x * 4 + wave;              // i in [0, 8192); i = v*B + b
    int v = row >> 12, b = row & (BATCH - 1);
    const float2* src = (const float2*)(feat + ((size_t)b * 2 + v) * DD);
    float2 x = src[lane];
    float ss = x.x * x.x + x.y * x.y;
    #pragma unroll
    for (int m = 32; m >= 1; m >>= 1) ss += __shfl_xor(ss, m, 64);
    float inv = rsqrtf(ss);
    ushort2 o;
    o.x = f2bf(x.x * inv);
    o.y = f2bf(x.y * inv);
    ((ushort2*)(nf + (size_t)row * DD))[lane] = o;
}

// Pass 1: neg_sum[i] = sum_j exp(logit_ij) * [lab(i) != lab(j)].
// Block = 4 waves stacked vertically: 256 rows; strip of 512 cols (8 col-tiles of 64).
// Wave tile = 64 rows x 64 cols via 16 x (16x16x32 bf16 MFMA) per kstep, K=128 = 4 ksteps.
// A frags (the wave's 64 rows) hoisted out of the column loop.
__global__ __launch_bounds__(256, 2) void k_negsum(
        const unsigned short* __restrict__ nf,
        const int* __restrict__ labels,
        float* __restrict__ neg_sum) {
    int wave = threadIdx.x >> 6, lane = threadIdx.x & 63;
    int q = lane >> 4, nq = lane & 15;
    int rowBase = blockIdx.x * 256 + wave * 64;
    int colBase = blockIdx.y * 512;
    const bf16x8* nfv = (const bf16x8*)nf;        // row stride = 16 chunks of 8 bf16

    // A-operand layout (16x16x32): lane holds A[m = lane&15][k = (lane>>4)*8 + j]
    bf16x8 aF[4][4];
    #pragma unroll
    for (int rs = 0; rs < 4; ++rs) {
        int r = rowBase + rs * 16 + nq;
        #pragma unroll
        for (int s = 0; s < 4; ++s) aF[rs][s] = nfv[r * 16 + s * 4 + q];
    }
    int rlab[4][4];
    float rowsum[4][4];
    #pragma unroll
    for (int rs = 0; rs < 4; ++rs)
        #pragma unroll
        for (int rr = 0; rr < 4; ++rr) {
            rlab[rs][rr] = labels[(rowBase + rs * 16 + q * 4 + rr) & (BATCH - 1)];
            rowsum[rs][rr] = 0.0f;
        }

    for (int ct = 0; ct < 8; ++ct) {
        int colTile = colBase + ct * 64;
        f32x4 acc[4][4];
        #pragma unroll
        for (int rs = 0; rs < 4; ++rs)
            #pragma unroll
            for (int cs = 0; cs < 4; ++cs) acc[rs][cs] = (f32x4){0.f, 0.f, 0.f, 0.f};
        #pragma unroll
        for (int s = 0; s < 4; ++s) {
            bf16x8 bF[4];   // B[k][n]: lane holds n = lane&15, k = (lane>>4)*8 + j
            #pragma unroll
            for (int cs = 0; cs < 4; ++cs)
                bF[cs] = nfv[(colTile + cs * 16 + nq) * 16 + s * 4 + q];
            #pragma unroll
            for (int rs = 0; rs < 4; ++rs)
                #pragma unroll
                for (int cs = 0; cs < 4; ++cs)
                    acc[rs][cs] = __builtin_amdgcn_mfma_f32_16x16x32_bf16(
                        aF[rs][s], bF[cs], acc[rs][cs], 0, 0, 0);
        }
        // C/D layout: col = lane&15, row = (lane>>4)*4 + reg
        #pragma unroll
        for (int cs = 0; cs < 4; ++cs) {
            int col = colTile + cs * 16 + nq;
            int cl = labels[col & (BATCH - 1)];
            #pragma unroll
            for (int rs = 0; rs < 4; ++rs)
                #pragma unroll
                for (int rr = 0; rr < 4; ++rr) {
                    float e = __expf(acc[rs][cs][rr] * (1.0f / 0.07f));
                    if (rlab[rs][rr] != cl) rowsum[rs][rr] += e;
                }
        }
    }
    // reduce across the 16 column-lanes of each quad, then one atomic per row
    #pragma unroll
    for (int rs = 0; rs < 4; ++rs)
        #pragma unroll
        for (int rr = 0; rr < 4; ++rr) {
            float vsum = rowsum[rs][rr];
            vsum += __shfl_xor(vsum, 1, 64);
            vsum += __shfl_xor(vsum, 2, 64);
            vsum += __shfl_xor(vsum, 4, 64);
            vsum += __shfl_xor(vsum, 8, 64);
            if (nq == 0) atomicAdd(&neg_sum[rowBase + rs * 16 + q * 4 + rr], vsum);
        }
}

// Pass 2: total += sum over positive pairs (i != j, same label) of
//         logit_ij - log(neg_sum[j] + exp(logit_ij)).
__global__ __launch_bounds__(256, 2) void k_loss(
        const unsigned short* __restrict__ nf,
        const int* __restrict__ labels,
        const float* __restrict__ neg_sum,
        float* __restrict__ total) {
    int wave = threadIdx.x >> 6, lane = threadIdx.x & 63;
    int q = lane >> 4, nq = lane & 15;
    int rowBase = blockIdx.x * 256 + wave * 64;
    int colBase = blockIdx.y * 512;
    const bf16x8* nfv = (const bf16x8*)nf;

    bf16x8 aF[4][4];
    #pragma unroll
    for (int rs = 0; rs < 4; ++rs) {
        int r = rowBase + rs * 16 + nq;
        #pragma unroll
        for (int s = 0; s < 4; ++s) aF[rs][s] = nfv[r * 16 + s * 4 + q];
    }
    int rlab[4][4];
    #pragma unroll
    for (int rs = 0; rs < 4; ++rs)
        #pragma unroll
        for (int rr = 0; rr < 4; ++rr)
            rlab[rs][rr] = labels[(rowBase + rs * 16 + q * 4 + rr) & (BATCH - 1)];

    float partial = 0.0f;
    for (int ct = 0; ct < 8; ++ct) {
        int colTile = colBase + ct * 64;
        f32x4 acc[4][4];
        #pragma unroll
        for (int rs = 0; rs < 4; ++rs)
            #pragma unroll
            for (int cs = 0; cs < 4; ++cs) acc[rs][cs] = (f32x4){0.f, 0.f, 0.f, 0.f};
        #pragma unroll
        for (int s = 0; s < 4; ++s) {
            bf16x8 bF[4];
            #pragma unroll
            for (int cs = 0; cs < 4; ++cs)
                bF[cs] = nfv[(colTile + cs * 16 + nq) * 16 + s * 4 + q];
            #pragma unroll
            for (int rs = 0; rs < 4; ++rs)
                #pragma unroll
                for (int cs = 0; cs < 4; ++cs)
                    acc[rs][cs] = __builtin_amdgcn_mfma_f32_16x16x32_bf16(
                        aF[rs][s], bF[cs], acc[rs][cs], 0, 0, 0);
        }
        #pragma unroll
        for (int cs = 0; cs < 4; ++cs) {
            int col = colTile + cs * 16 + nq;
            int cl = labels[col & (BATCH - 1)];
            float ns = neg_sum[col];
            #pragma unroll
            for (int rs = 0; rs < 4; ++rs)
                #pragma unroll
                for (int rr = 0; rr < 4; ++rr) {
                    int row = rowBase + rs * 16 + q * 4 + rr;
                    if (rlab[rs][rr] == cl && row != col) {   // ~1% taken
                        float logit = acc[rs][cs][rr] * (1.0f / 0.07f);
                        float e = __expf(logit);
                        partial += logit - __logf(ns + e);
                    }
                }
        }
    }
    #pragma unroll
    for (int m = 32; m >= 1; m >>= 1) partial += __shfl_xor(partial, m, 64);
    __shared__ float red[4];
    if (lane == 0) red[wave] = partial;
    __syncthreads();
    if (threadIdx.x == 0) {
        atomicAdd(total, red[0] + red[1] + red[2] + red[3]);
    }
}

__global__ void k_final(const float* __restrict__ total, float* __restrict__ out) {
    out[0] = -total[0] * (1.0f / (float)NN);    // T/baseT = 1
}

extern "C" void kernel_launch(void* const* d_in, const int* in_sizes, int n_in,
                              void* d_out, int out_size, void* d_ws, size_t ws_size,
                              hipStream_t stream) {
    const float* feat = (const float*)d_in[0];
    const int* labels = (const int*)d_in[1];
    unsigned short* nf = (unsigned short*)d_ws;
    float* neg_sum = (float*)((char*)d_ws + (size_t)NN * DD * sizeof(unsigned short));
    float* total = neg_sum + NN;
    float* out = (float*)d_out;

    hipLaunchKernelGGL(k_zero, dim3((NN + 1 + 255) / 256), dim3(256), 0, stream, neg_sum, NN + 1);
    hipLaunchKernelGGL(k_normalize, dim3(NN / 4), dim3(256), 0, stream, feat, nf);
    hipLaunchKernelGGL(k_negsum, dim3(32, 16), dim3(256), 0, stream, nf, labels, neg_sum);
    hipLaunchKernelGGL(k_loss, dim3(32, 16), dim3(256), 0, stream, nf, labels, neg_sum, total);
    hipLaunchKernelGGL(k_final, dim3(1), dim3(1), 0, stream, total, out);
}

// Round 2
// 143.754 us; speedup vs baseline: 1.0849x; 1.0849x over previous
//
#include <hip/hip_runtime.h>

// SupConLoss on MI355X. features: [4096, 2, 128] fp32; labels: [4096] int; out: 1 f32.
//
// R1 changes vs R0:
//  - k_loss (full 8192x8192 matmul, 64us) replaced by label-bucketed positive-pair
//    gather (k_pairs + 3 tiny bucket-building kernels). Only ~1% of pairs are positive.
//  - k_negsum grid 512 -> 1024 blocks (col strip 512 -> 256) to lift occupancy
//    from 2 to 4+ blocks/CU (VGPR=96 allows 5).
//
// ws layout (words are 4B):
//   [0, 2 MB)              nf       : 8192 x 128 bf16 (normalized, row i = v*4096 + b)
//   nf + 2MB:              neg_sum  : 8192 f32      (zeroed)
//   + total    : 1 f32     (zeroed)
//   + counts   : 100 int   (zeroed)
//   + cursor   : 100 int   (zeroed)
//   + offsets  : 101 int
//   + classIdx : 4096 int

#define BATCH 4096
#define NN    8192
#define DD    128
#define NCLS  100
#define MAXR  192    // max class rows (2*members) staged in LDS; P(exceed) ~ 0

typedef __attribute__((ext_vector_type(8))) short bf16x8;
typedef __attribute__((ext_vector_type(4))) float f32x4;

__device__ __forceinline__ unsigned short f2bf(float f) {
    unsigned u = __float_as_uint(f);
    u += 0x7FFF + ((u >> 16) & 1);
    return (unsigned short)(u >> 16);
}

__global__ void k_zero(float* p, int n) {
    int i = blockIdx.x * 256 + threadIdx.x;
    if (i < n) p[i] = 0.0f;
}

__global__ void k_normalize(const float* __restrict__ feat, unsigned short* __restrict__ nf) {
    int wave = threadIdx.x >> 6, lane = threadIdx.x & 63;
    int row = blockIdx.x * 4 + wave;
    int v = row >> 12, b = row & (BATCH - 1);
    const float2* src = (const float2*)(feat + ((size_t)b * 2 + v) * DD);
    float2 x = src[lane];
    float ss = x.x * x.x + x.y * x.y;
    #pragma unroll
    for (int m = 32; m >= 1; m >>= 1) ss += __shfl_xor(ss, m, 64);
    float inv = rsqrtf(ss);
    ushort2 o;
    o.x = f2bf(x.x * inv);
    o.y = f2bf(x.y * inv);
    ((ushort2*)(nf + (size_t)row * DD))[lane] = o;
}

// ---- class bucketing ----
__global__ void k_count(const int* __restrict__ labels, int* __restrict__ counts) {
    int b = blockIdx.x * 256 + threadIdx.x;
    if (b < BATCH) atomicAdd(&counts[labels[b]], 1);
}
__global__ void k_scan(const int* __restrict__ counts, int* __restrict__ offsets) {
    if (threadIdx.x == 0) {
        int acc = 0;
        for (int c = 0; c < NCLS; ++c) { offsets[c] = acc; acc += counts[c]; }
        offsets[NCLS] = acc;
    }
}
__global__ void k_scatter(const int* __restrict__ labels, const int* __restrict__ offsets,
                          int* __restrict__ cursor, int* __restrict__ classIdx) {
    int b = blockIdx.x * 256 + threadIdx.x;
    if (b < BATCH) {
        int l = labels[b];
        int pos = atomicAdd(&cursor[l], 1);
        classIdx[offsets[l] + pos] = b;
    }
}

// ---- pass 1: neg_sum[i] = sum_j exp(logit_ij) [lab(i)!=lab(j)] ----
__global__ __launch_bounds__(256, 2) void k_negsum(
        const unsigned short* __restrict__ nf,
        const int* __restrict__ labels,
        float* __restrict__ neg_sum) {
    int wave = threadIdx.x >> 6, lane = threadIdx.x & 63;
    int q = lane >> 4, nq = lane & 15;
    int rowBase = blockIdx.x * 256 + wave * 64;
    int colBase = blockIdx.y * 256;
    const bf16x8* nfv = (const bf16x8*)nf;

    bf16x8 aF[4][4];
    #pragma unroll
    for (int rs = 0; rs < 4; ++rs) {
        int r = rowBase + rs * 16 + nq;
        #pragma unroll
        for (int s = 0; s < 4; ++s) aF[rs][s] = nfv[r * 16 + s * 4 + q];
    }
    int rlab[4][4];
    float rowsum[4][4];
    #pragma unroll
    for (int rs = 0; rs < 4; ++rs)
        #pragma unroll
        for (int rr = 0; rr < 4; ++rr) {
            rlab[rs][rr] = labels[(rowBase + rs * 16 + q * 4 + rr) & (BATCH - 1)];
            rowsum[rs][rr] = 0.0f;
        }

    for (int ct = 0; ct < 4; ++ct) {
        int colTile = colBase + ct * 64;
        f32x4 acc[4][4];
        #pragma unroll
        for (int rs = 0; rs < 4; ++rs)
            #pragma unroll
            for (int cs = 0; cs < 4; ++cs) acc[rs][cs] = (f32x4){0.f, 0.f, 0.f, 0.f};
        #pragma unroll
        for (int s = 0; s < 4; ++s) {
            bf16x8 bF[4];
            #pragma unroll
            for (int cs = 0; cs < 4; ++cs)
                bF[cs] = nfv[(colTile + cs * 16 + nq) * 16 + s * 4 + q];
            #pragma unroll
            for (int rs = 0; rs < 4; ++rs)
                #pragma unroll
                for (int cs = 0; cs < 4; ++cs)
                    acc[rs][cs] = __builtin_amdgcn_mfma_f32_16x16x32_bf16(
                        aF[rs][s], bF[cs], acc[rs][cs], 0, 0, 0);
        }
        #pragma unroll
        for (int cs = 0; cs < 4; ++cs) {
            int col = colTile + cs * 16 + nq;
            int cl = labels[col & (BATCH - 1)];
            #pragma unroll
            for (int rs = 0; rs < 4; ++rs)
                #pragma unroll
                for (int rr = 0; rr < 4; ++rr) {
                    float e = __expf(acc[rs][cs][rr] * (1.0f / 0.07f));
                    if (rlab[rs][rr] != cl) rowsum[rs][rr] += e;
                }
        }
    }
    #pragma unroll
    for (int rs = 0; rs < 4; ++rs)
        #pragma unroll
        for (int rr = 0; rr < 4; ++rr) {
            float vsum = rowsum[rs][rr];
            vsum += __shfl_xor(vsum, 1, 64);
            vsum += __shfl_xor(vsum, 2, 64);
            vsum += __shfl_xor(vsum, 4, 64);
            vsum += __shfl_xor(vsum, 8, 64);
            if (nq == 0) atomicAdd(&neg_sum[rowBase + rs * 16 + q * 4 + rr], vsum);
        }
}

// ---- pass 2: positive pairs only ----
// grid (NCLS, SLICES). Per class: stage 2m rows in LDS, each thread walks a slice
// of the (2m)^2 ordered pair space, accumulating logit - log(ns_j + exp(logit)).
#define SLICES 4
__global__ __launch_bounds__(256) void k_pairs(
        const unsigned short* __restrict__ nf,
        const int* __restrict__ counts, const int* __restrict__ offsets,
        const int* __restrict__ classIdx,
        const float* __restrict__ neg_sum,
        float* __restrict__ total) {
    __shared__ int s_rows[MAXR];
    __shared__ unsigned short s_feat[MAXR * 136];   // +8 pad: break LDS bank aliasing
    int c = blockIdx.x;
    int m = counts[c];
    int off = offsets[c];
    int twoM = 2 * m;
    int tid = threadIdx.x;
    int ldsRows = twoM < MAXR ? twoM : MAXR;

    for (int r = tid; r < twoM; r += 256) {
        int b = classIdx[off + (r < m ? r : r - m)];
        int row = (r < m) ? b : b + BATCH;
        if (r < MAXR) s_rows[r] = row;
    }
    __syncthreads();
    for (int ch = tid; ch < ldsRows * 16; ch += 256) {
        int r = ch >> 4, s = ch & 15;
        const uint4* src = (const uint4*)(nf + (size_t)s_rows[r] * DD);
        *(uint4*)&s_feat[r * 136 + s * 8] = src[s];
    }
    __syncthreads();

    float partial = 0.0f;
    unsigned P = (unsigned)twoM * (unsigned)twoM;
    for (unsigned t = blockIdx.y * 256 + tid; t < P; t += 256 * SLICES) {
        unsigned p = t / (unsigned)twoM;
        unsigned qq = t - p * (unsigned)twoM;
        if (p == qq) continue;
        // dot(row p, row q) in fp32 from bf16
        float dot = 0.0f;
        if ((int)p < MAXR && (int)qq < MAXR) {
            #pragma unroll 4
            for (int s = 0; s < 16; ++s) {
                uint4 ua = *(const uint4*)&s_feat[p * 136 + s * 8];
                uint4 ub = *(const uint4*)&s_feat[qq * 136 + s * 8];
                const unsigned* pa = (const unsigned*)&ua;
                const unsigned* pb = (const unsigned*)&ub;
                #pragma unroll
                for (int w = 0; w < 4; ++w) {
                    float a0 = __uint_as_float(pa[w] << 16);
                    float a1 = __uint_as_float(pa[w] & 0xFFFF0000u);
                    float b0 = __uint_as_float(pb[w] << 16);
                    float b1 = __uint_as_float(pb[w] & 0xFFFF0000u);
                    dot = fmaf(a0, b0, dot);
                    dot = fmaf(a1, b1, dot);
                }
            }
        } else {  // overflow fallback (never taken for random labels)
            int rp = (int)p < MAXR ? s_rows[p] : 0;
            int rq = (int)qq < MAXR ? s_rows[qq] : 0;
            // recompute row ids directly from classIdx for safety
            rp = ((int)p < m) ? classIdx[off + p] : classIdx[off + p - m] + BATCH;
            rq = ((int)qq < m) ? classIdx[off + qq] : classIdx[off + qq - m] + BATCH;
            for (int d = 0; d < DD; ++d) {
                float a = __uint_as_float(((unsigned)nf[(size_t)rp * DD + d]) << 16);
                float b = __uint_as_float(((unsigned)nf[(size_t)rq * DD + d]) << 16);
                dot = fmaf(a, b, dot);
            }
        }
        int rj = ((int)qq < m) ? classIdx[off + qq] : classIdx[off + qq - m] + BATCH;
        float ns = neg_sum[rj];
        float logit = dot * (1.0f / 0.07f);
        partial += logit - __logf(ns + __expf(logit));
    }
    #pragma unroll
    for (int mm = 32; mm >= 1; mm >>= 1) partial += __shfl_xor(partial, mm, 64);
    __shared__ float red[4];
    if ((tid & 63) == 0) red[tid >> 6] = partial;
    __syncthreads();
    if (tid == 0) atomicAdd(total, red[0] + red[1] + red[2] + red[3]);
}

__global__ void k_final(const float* __restrict__ total, float* __restrict__ out) {
    out[0] = -total[0] * (1.0f / (float)NN);
}

extern "C" void kernel_launch(void* const* d_in, const int* in_sizes, int n_in,
                              void* d_out, int out_size, void* d_ws, size_t ws_size,
                              hipStream_t stream) {
    const float* feat = (const float*)d_in[0];
    const int* labels = (const int*)d_in[1];
    unsigned short* nf = (unsigned short*)d_ws;
    float* neg_sum = (float*)((char*)d_ws + (size_t)NN * DD * sizeof(unsigned short));
    float* total   = neg_sum + NN;          // 1
    int* counts    = (int*)(total + 1);     // 100
    int* cursor    = counts + NCLS;         // 100
    int* offsets   = cursor + NCLS;         // 101
    int* classIdx  = offsets + NCLS + 1;    // 4096
    float* out = (float*)d_out;

    int zeroN = NN + 1 + NCLS + NCLS;       // neg_sum, total, counts, cursor (contiguous)
    hipLaunchKernelGGL(k_zero, dim3((zeroN + 255) / 256), dim3(256), 0, stream, neg_sum, zeroN);
    hipLaunchKernelGGL(k_normalize, dim3(NN / 4), dim3(256), 0, stream, feat, nf);
    hipLaunchKernelGGL(k_count, dim3(BATCH / 256), dim3(256), 0, stream, labels, counts);
    hipLaunchKernelGGL(k_scan, dim3(1), dim3(64), 0, stream, counts, offsets);
    hipLaunchKernelGGL(k_scatter, dim3(BATCH / 256), dim3(256), 0, stream, labels, offsets, cursor, classIdx);
    hipLaunchKernelGGL(k_negsum, dim3(32, 32), dim3(256), 0, stream, nf, labels, neg_sum);
    hipLaunchKernelGGL(k_pairs, dim3(NCLS, SLICES), dim3(256), 0, stream,
                       nf, counts, offsets, classIdx, neg_sum, total);
    hipLaunchKernelGGL(k_final, dim3(1), dim3(1), 0, stream, total, out);
}